// Round 3
// baseline (701.742 us; speedup 1.0000x reference)
//
#include <hip/hip_runtime.h>
#include <hip/hip_bf16.h>

#define BB 32
#define LL 200
#define DD 768
#define SS 1556
#define MAXM 6400   // per-kk flattened row capacity (32 * (199-kk) < 6400)

typedef __attribute__((ext_vector_type(8))) short bf16x8;   // 8 bf16 = 4 VGPRs (MFMA A/B frag)
typedef __attribute__((ext_vector_type(4))) float floatx4;  // MFMA C/D frag

__device__ __forceinline__ float bf2f(ushort u){
    union { unsigned int i; float f; } v; v.i = ((unsigned int)u) << 16; return v.f;
}
__device__ __forceinline__ ushort f2bf(float f){
    union { float f; unsigned int i; } v; v.f = f;
    unsigned int x = v.i;
    return (ushort)((x + 0x7FFFu + ((x >> 16) & 1u)) >> 16);  // RNE, inputs finite
}

// ---------------------------------------------------------------------------
// Kernel 0: dtype detector (flag=1 -> bf16 data, flag=0 -> float32).
// ---------------------------------------------------------------------------
__global__ void detect_kernel(const unsigned int* __restrict__ feat_raw, int* __restrict__ flag){
    __shared__ int cnt_s;
    if (threadIdx.x == 0) cnt_s = 0;
    __syncthreads();
    int c = 0;
    for (int i = threadIdx.x; i < 4096; i += 256){
        unsigned int w = feat_raw[i];
        unsigned int e = (w >> 7) & 0xFFu;
        if (e >= 100u && e <= 150u) c++;
    }
    atomicAdd(&cnt_s, c);
    __syncthreads();
    if (threadIdx.x == 0) *flag = (cnt_s > 2457) ? 1 : 0;
}

// ---------------------------------------------------------------------------
// Kernel 1: per-batch span offsets. offs[b][0..8]; counts[k] = max(n-k-2, 0).
// ---------------------------------------------------------------------------
__global__ void offs_kernel(const int* __restrict__ mask, int* __restrict__ offs){
    int b = blockIdx.x;
    int lane = threadIdx.x;
    int s = 0;
    for (int i = lane; i < LL; i += 64) s += mask[b*LL + i];
    #pragma unroll
    for (int d = 32; d > 0; d >>= 1) s += __shfl_down(s, d, 64);
    if (lane == 0){
        int n = s, cum = 0;
        offs[b*9 + 0] = 0;
        for (int j = 0; j < 8; ++j){
            int c = n - j - 2; if (c < 0) c = 0;
            cum += c;
            offs[b*9 + j + 1] = cum;
        }
    }
}

// ---------------------------------------------------------------------------
// Kernel 1b: flattened-M row maps per width bucket.
// ---------------------------------------------------------------------------
__global__ void maps_kernel(const int* __restrict__ offs, int* __restrict__ pfx,
                            int* __restrict__ amap, int* __restrict__ omap){
    const int kkidx = blockIdx.x;
    const int kk = kkidx + 2;
    __shared__ int P[33];
    __shared__ int base_s[32];
    const int tid = threadIdx.x;
    if (tid == 0){
        int acc = 0; P[0] = 0;
        for (int b = 0; b < 32; ++b){
            acc += offs[b*9 + kk] - offs[b*9 + kk - 1];
            P[b+1] = acc;
        }
    }
    if (tid < 32) base_s[tid] = offs[tid*9 + kk - 1];
    __syncthreads();
    if (tid == 0) pfx[kkidx*33 + 32] = P[32];
    const int Mtot = P[32];
    for (int r = tid; r < MAXM; r += 256){
        int b = 0;
        #pragma unroll
        for (int i = 1; i <= 32; ++i) b += (P[i] <= r) ? 1 : 0;
        int bb = b < 32 ? b : 31;
        int larow = (r < Mtot) ? (r - P[bb]) : 0;   // clamp OOB rows to a safe row
        amap[kkidx*MAXM + r] = bb*LL + larow + 1;
        omap[kkidx*MAXM + r] = bb*SS + base_s[bb] + larow;
    }
}

// ---------------------------------------------------------------------------
// Kernel 2: ALL widths' weight repack in ONE launch. grid=(192, 7).
// ---------------------------------------------------------------------------
__global__ void repack2_kernel(const void* __restrict__ w2, const void* __restrict__ w3,
                               const void* __restrict__ w4, const void* __restrict__ w5,
                               const void* __restrict__ w6, const void* __restrict__ w7,
                               const void* __restrict__ w8,
                               const void* __restrict__ b2, const void* __restrict__ b3,
                               const void* __restrict__ b4, const void* __restrict__ b5,
                               const void* __restrict__ b6, const void* __restrict__ b7,
                               const void* __restrict__ b8,
                               ushort* __restrict__ BpAll, float* __restrict__ biasF,
                               const int* __restrict__ flag){
    const size_t PRE[7] = {0, 2, 5, 9, 14, 20, 27};
    const int kkidx = blockIdx.y;
    const int kk = kkidx + 2;
    const void* w  = kkidx==0?w2:kkidx==1?w3:kkidx==2?w4:kkidx==3?w5:kkidx==4?w6:kkidx==5?w7:w8;
    const void* bv = kkidx==0?b2:kkidx==1?b3:kkidx==2?b4:kkidx==3?b5:kkidx==4?b6:kkidx==5?b7:b8;
    ushort* Bp = BpAll + PRE[kkidx]*589824;

    const int bfm = *flag;
    __shared__ ushort lds[24576];         // 4 rows x 768*8 max (49152 B)
    const int tid = threadIdx.x;
    const int ob  = blockIdx.x;           // 4 output channels each
    const int rowlen = DD * kk;
    const int nelem  = 4 * rowlen;

    if (bfm){
        const ushort* src = (const ushort*)w + (size_t)ob * nelem;
        const int nch = nelem >> 3;
        for (int c = tid; c < nch; c += 256)
            __builtin_memcpy(lds + c*8, src + c*8, 16);
        if (ob == 0)
            for (int i = tid; i < DD; i += 256) biasF[kkidx*DD + i] = bf2f(((const ushort*)bv)[i]);
    } else {
        const float* src = (const float*)w + (size_t)ob * nelem;
        const int nch = nelem >> 2;
        for (int c = tid; c < nch; c += 256){
            float t4[4];
            __builtin_memcpy(t4, src + c*4, 16);
            #pragma unroll
            for (int j2 = 0; j2 < 4; ++j2) lds[c*4 + j2] = f2bf(t4[j2]);
        }
        if (ob == 0)
            for (int i = tid; i < DD; i += 256) biasF[kkidx*DD + i] = ((const float*)bv)[i];
    }
    __syncthreads();

    const int total = 96 * kk * 4;
    for (int c = tid; c < total; c += 256){
        int jb = c >> 2, ol = c & 3;
        int j0 = jb * 8;
        int t  = j0 / 768;
        int i0 = j0 - t * 768;
        ushort tmp[8];
        #pragma unroll
        for (int jj = 0; jj < 8; ++jj)
            tmp[jj] = lds[ol*rowlen + (i0 + jj)*kk + t];
        int o = ob*4 + ol;
        __builtin_memcpy(Bp + (size_t)jb*6144 + (size_t)o*8, tmp, 16);
    }
}

// ---------------------------------------------------------------------------
// Kernel 2b: features -> bf16 A-source buffer.
// ---------------------------------------------------------------------------
__global__ void cvtA_kernel(const void* __restrict__ feat, ushort* __restrict__ featbf,
                            const int* __restrict__ flag){
    const int bfm = *flag;
    int idx = blockIdx.x*256 + threadIdx.x;
    const int TOT = BB*LL*DD/8;
    if (idx >= TOT) return;
    if (bfm){
        __builtin_memcpy(featbf + (size_t)idx*8, (const ushort*)feat + (size_t)idx*8, 16);
    } else {
        float t8[8];
        __builtin_memcpy(t8,     (const float*)feat + (size_t)idx*8,     16);
        __builtin_memcpy(t8 + 4, (const float*)feat + (size_t)idx*8 + 4, 16);
        ushort o8[8];
        #pragma unroll
        for (int j = 0; j < 8; ++j) o8[j] = f2bf(t8[j]);
        __builtin_memcpy(featbf + (size_t)idx*8, o8, 16);
    }
}

// ---------------------------------------------------------------------------
// Kernel 3: unigram copy + zero invalid + valid flags (native dtype).
// ---------------------------------------------------------------------------
__global__ void fill_kernel(const void* __restrict__ feat, const int* __restrict__ offs,
                            void* __restrict__ out, const int* __restrict__ flag){
    const int bfm = *flag;
    int idx = blockIdx.x*256 + threadIdx.x;
    const int TOT = BB*SS*192;
    if (idx >= TOT) return;
    int b = idx / (SS*192);
    int r = idx - b*(SS*192);
    int s = r / 192;
    int c = r - s*192;
    int c0  = offs[b*9 + 1];
    int tot = offs[b*9 + 8];
    if (bfm){
        if (c < 96){
            ushort* dst = (ushort*)out + ((size_t)b*SS + s)*768 + c*8;
            if (s < c0){
                const ushort* srcp = (const ushort*)feat + ((size_t)b*LL + s + 1)*768 + c*8;
                __builtin_memcpy(dst, srcp, 16);
            } else if (s >= tot){
                const ushort z[8] = {0,0,0,0,0,0,0,0};
                __builtin_memcpy(dst, z, 16);
            }
        }
        if (c == 0)
            ((ushort*)out)[(size_t)BB*SS*768 + (size_t)b*SS + s] = (s < tot) ? (ushort)0x3F80 : (ushort)0;
    } else {
        float* dst = (float*)out + ((size_t)b*SS + s)*768 + c*4;
        if (s < c0){
            const float* srcp = (const float*)feat + ((size_t)b*LL + s + 1)*768 + c*4;
            __builtin_memcpy(dst, srcp, 16);
        } else if (s >= tot){
            const float z[4] = {0.f,0.f,0.f,0.f};
            __builtin_memcpy(dst, z, 16);
        }
        if (c == 0)
            ((float*)out)[(size_t)BB*SS*768 + (size_t)b*SS + s] = (s < tot) ? 1.0f : 0.0f;
    }
}

// ---------------------------------------------------------------------------
// Kernel 4 (v3b): flattened-M 128x128-tile GEMM with counted-vmcnt pipeline.
//  - 3 LDS B-buffers (48 KB), stage depth 2 via global_load_lds
//  - A fragments double-buffered in registers, issued 1 chunk ahead
//  - raw s_barrier + asm s_waitcnt vmcnt(12) ("memory" clobber pins IR-level
//    ordering; sched_barrier(0) pins the machine scheduler): prefetch loads
//    stay IN FLIGHT across barriers (T3+T4) instead of draining vmcnt(0)
//  - 6-substep unrolled macro-iterations -> all buffer indices static
//  - T5 setprio(1) around the MFMA cluster
//  - XCD-aware static schedule (unchanged from v2)
// ---------------------------------------------------------------------------
__global__ __launch_bounds__(256) void conv_gemm4(const ushort* __restrict__ featbf,
        const ushort* __restrict__ BpAll, const float* __restrict__ biasF,
        const int* __restrict__ pfx, const int* __restrict__ amap,
        const int* __restrict__ omap, void* __restrict__ out,
        const int* __restrict__ flag){
    const size_t PRE[7] = {0, 2, 5, 9, 14, 20, 27};
    const int GCNT[8]     = {5,5,5,5,5,5,6,6};
    const int GLIST[8][6] = {
        {36,37,38, 0, 4, 0},
        {39,40,41, 1, 5, 0},
        {30,31,32, 6, 2, 0},
        {33,34,35, 7, 3, 0},
        {24,25,26,12,13, 0},
        {27,28,29,14,15, 0},
        {18,19,20,16, 8,10},
        {21,22,23,17, 9,11},
    };
    const int n   = blockIdx.x;
    const int xcd = n & 7;
    const int is  = n >> 3;
    const int cx  = GCNT[xcd];
    if (is >= cx * 50) return;
    const int gi = is % cx;
    const int mt = is / cx;
    const int g  = GLIST[xcd][gi];
    const int kkidx = g / 6;
    const int nt = g - kkidx*6;
    const int kk = kkidx + 2;
    const int Mtot = pfx[kkidx*33 + 32];
    const int m0 = mt * 128;
    if (m0 >= Mtot) return;
    const int n0 = nt * 128;
    const int bfm = *flag;

    __shared__ ushort Bs[3][8192];         // 3 x 16 KB: 8 planes x 128 cols x 8

    const int tid  = threadIdx.x;
    const int wv   = tid >> 6;
    const int wvm  = wv >> 1;              // wave row (0..1)
    const int wvn  = wv & 1;               // wave col (0..1)
    const int lane = tid & 63;
    const int quad = lane >> 4;
    const int l15  = lane & 15;
    const int wvbase = tid & 192;          // wv*64 (wave-uniform)

    // A row base pointers for the 4 m-subtiles of this wave-row
    const ushort* Abase[4];
    #pragma unroll
    for (int sm = 0; sm < 4; ++sm){
        int r = kkidx*MAXM + m0 + wvm*64 + sm*16 + l15;
        Abase[sm] = featbf + (size_t)amap[r]*768 + quad*8;
    }

    floatx4 acc[4][4];
    #pragma unroll
    for (int sn = 0; sn < 4; ++sn){
        float bv = biasF[kkidx*768 + n0 + wvn*64 + sn*16 + l15];
        #pragma unroll
        for (int sm = 0; sm < 4; ++sm){
            acc[sm][sn][0] = bv; acc[sm][sn][1] = bv;
            acc[sm][sn][2] = bv; acc[sm][sn][3] = bv;
        }
    }

    // B source: per-lane base; plane p = (tid>>7), col = n0 + (tid&127)
    const ushort* BkkBase = BpAll + PRE[kkidx]*589824;
    const ushort* bsrc0 = BkkBase + (size_t)(tid >> 7)*6144 + (size_t)(n0 + (tid & 127))*8;
    char* bsLin = (char*)&Bs[0][0];
    const int nchunks = kk * 12;           // K / 64, divisible by 6

    bf16x8 aA[2][4], aB[2][4];             // two A register sets (static names)

    #define STAGE_B(BUF, ch) do { \
        const ushort* gb_ = bsrc0 + (size_t)(ch)*8*6144; \
        _Pragma("unroll") \
        for (int ii_ = 0; ii_ < 4; ++ii_){ \
            __builtin_amdgcn_global_load_lds( \
                (const __attribute__((address_space(1))) void*)(gb_ + (size_t)ii_*2*6144), \
                (__attribute__((address_space(3))) void*)(bsLin + (BUF)*16384 + (ii_*256 + wvbase)*16), \
                16, 0, 0); \
        } } while(0)

    #define LOAD_A(dst, ch) do { \
        const int koff_ = (ch)*64; \
        _Pragma("unroll") \
        for (int ks_ = 0; ks_ < 2; ++ks_) \
            _Pragma("unroll") \
            for (int sm_ = 0; sm_ < 4; ++sm_) \
                __builtin_memcpy(&dst[ks_][sm_], Abase[sm_] + koff_ + ks_*32, 16); \
        } while(0)

    #define COMPUTE(BUF, areg) do { \
        __builtin_amdgcn_s_setprio(1); \
        _Pragma("unroll") \
        for (int ks_ = 0; ks_ < 2; ++ks_){ \
            const int pl_ = ks_*4 + quad; \
            bf16x8 bfr[4]; \
            _Pragma("unroll") \
            for (int sn_ = 0; sn_ < 4; ++sn_) \
                __builtin_memcpy(&bfr[sn_], &Bs[BUF][pl_*1024 + (wvn*64 + sn_*16 + l15)*8], 16); \
            _Pragma("unroll") \
            for (int sm_ = 0; sm_ < 4; ++sm_) \
                _Pragma("unroll") \
                for (int sn_ = 0; sn_ < 4; ++sn_) \
                    acc[sm_][sn_] = __builtin_amdgcn_mfma_f32_16x16x32_bf16( \
                        areg[ks_][sm_], bfr[sn_], acc[sm_][sn_], 0, 0, 0); \
        } \
        __builtin_amdgcn_s_setprio(0); \
        } while(0)

    // One pipelined substep. Steady state after the wait: 12 ops in flight
    // (B(ch+2): 4 gload_lds, A(ch+1): 8 dwordx4) -> chunk ch fully landed.
    #define SUBSTEP(CH, BIC, BIS, ACUR, ANXT, DOB, DOA, NW) do { \
        if (DOB) STAGE_B(BIS, (CH)+2); \
        if (DOA) LOAD_A(ANXT, (CH)+1); \
        __builtin_amdgcn_sched_barrier(0); \
        asm volatile("s_waitcnt vmcnt(" NW ")" ::: "memory"); \
        __builtin_amdgcn_sched_barrier(0); \
        __builtin_amdgcn_s_barrier(); \
        __builtin_amdgcn_sched_barrier(0); \
        COMPUTE(BIC, ACUR); \
        __builtin_amdgcn_s_barrier(); \
        __builtin_amdgcn_sched_barrier(0); \
    } while(0)

    // prologue: B(0)->buf0, B(1)->buf1, A(0)->aA   (FIFO: [B0,B1,A0])
    STAGE_B(0, 0);
    STAGE_B(1, 1);
    LOAD_A(aA, 0);

    const int nmac = kk * 2;               // nchunks / 6
    for (int j = 0; j < nmac - 1; ++j){
        const int ch = j * 6;
        SUBSTEP(ch+0, 0, 2, aA, aB, true, true, "12");
        SUBSTEP(ch+1, 1, 0, aB, aA, true, true, "12");
        SUBSTEP(ch+2, 2, 1, aA, aB, true, true, "12");
        SUBSTEP(ch+3, 0, 2, aB, aA, true, true, "12");
        SUBSTEP(ch+4, 1, 0, aA, aB, true, true, "12");
        SUBSTEP(ch+5, 2, 1, aB, aA, true, true, "12");
    }
    {   // epilogue macro-iteration: ch = nchunks-6
        const int ch = (nmac - 1) * 6;
        SUBSTEP(ch+0, 0, 2, aA, aB, true,  true,  "12");
        SUBSTEP(ch+1, 1, 0, aB, aA, true,  true,  "12");
        SUBSTEP(ch+2, 2, 1, aA, aB, true,  true,  "12");
        SUBSTEP(ch+3, 0, 2, aB, aA, true,  true,  "12");
        SUBSTEP(ch+4, 1, 0, aA, aB, false, true,  "8");
        SUBSTEP(ch+5, 2, 1, aB, aA, false, false, "0");
    }

    #undef SUBSTEP
    #undef STAGE_B
    #undef LOAD_A
    #undef COMPUTE

    // ---- epilogue: scatter rows to packed span slots ----
    #pragma unroll
    for (int sm = 0; sm < 4; ++sm){
        #pragma unroll
        for (int rr = 0; rr < 4; ++rr){
            int r = m0 + wvm*64 + sm*16 + quad*4 + rr;
            if (r < Mtot){
                int slot = omap[kkidx*MAXM + r];
                if (bfm){
                    ushort* oh = (ushort*)out;
                    #pragma unroll
                    for (int sn = 0; sn < 4; ++sn)
                        oh[(size_t)slot*768 + n0 + wvn*64 + sn*16 + l15] = f2bf(acc[sm][sn][rr]);
                } else {
                    float* of = (float*)out;
                    #pragma unroll
                    for (int sn = 0; sn < 4; ++sn)
                        of[(size_t)slot*768 + n0 + wvn*64 + sn*16 + l15] = acc[sm][sn][rr];
                }
            }
        }
    }
}

// ---------------------------------------------------------------------------
// Fallback (workspace too small): direct-from-raw-weights GEMM. Slow, correct.
// ---------------------------------------------------------------------------
__global__ __launch_bounds__(256) void conv_gemm_direct(const void* __restrict__ feat,
        const int* __restrict__ offs, void* __restrict__ out, const int* __restrict__ flag,
        const void* w2, const void* w3, const void* w4, const void* w5,
        const void* w6, const void* w7, const void* w8,
        const void* b2, const void* b3, const void* b4, const void* b5,
        const void* b6, const void* b7, const void* b8){
    const int bfm = *flag;
    const int kkidx = blockIdx.y;
    const int kk = kkidx + 2;
    const int b = blockIdx.z;
    const void* w  = kkidx==0?w2:kkidx==1?w3:kkidx==2?w4:kkidx==3?w5:kkidx==4?w6:kkidx==5?w7:w8;
    const void* bv = kkidx==0?b2:kkidx==1?b3:kkidx==2?b4:kkidx==3?b5:kkidx==4?b6:kkidx==5?b7:b8;

    const int off_j = offs[b*9 + kk - 1];
    const int cnt   = offs[b*9 + kk] - off_j;
    const int mt = blockIdx.x / 12;
    const int nt = blockIdx.x - mt*12;
    const int m0 = mt * 64;
    if (m0 >= cnt) return;
    const int n0 = nt * 64;

    const int tid  = threadIdx.x;
    const int wvv  = tid >> 6;
    const int lane = tid & 63;
    const int quad = lane >> 4;
    const int l15  = lane & 15;

    int row  = m0 + wvv*16 + l15;
    int arow = row < cnt ? row : cnt - 1;
    const size_t abase = ((size_t)b*LL + arow + 1)*768 + quad*8;

    floatx4 acc[4];
    #pragma unroll
    for (int cg = 0; cg < 4; ++cg){
        float bb = bfm ? bf2f(((const ushort*)bv)[n0 + cg*16 + l15])
                       : ((const float*)bv)[n0 + cg*16 + l15];
        acc[cg][0] = bb; acc[cg][1] = bb; acc[cg][2] = bb; acc[cg][3] = bb;
    }

    const int steps = kk * 24;
    for (int s = 0; s < steps; ++s){
        bf16x8 a;
        if (bfm){
            __builtin_memcpy(&a, (const ushort*)feat + abase + s*32, 16);
        } else {
            float t8[8];
            __builtin_memcpy(t8,     (const float*)feat + abase + s*32,     16);
            __builtin_memcpy(t8 + 4, (const float*)feat + abase + s*32 + 4, 16);
            ushort o8[8];
            #pragma unroll
            for (int j = 0; j < 8; ++j) o8[j] = f2bf(t8[j]);
            __builtin_memcpy(&a, o8, 16);
        }
        int j0 = s*32 + quad*8;
        int t  = j0 / 768;
        int i0 = j0 - t*768;
        #pragma unroll
        for (int cg = 0; cg < 4; ++cg){
            int o = n0 + cg*16 + l15;
            size_t wbase = (size_t)o*(DD*kk) + (size_t)i0*kk + t;
            ushort tmp[8];
            if (bfm){
                const ushort* wp = (const ushort*)w + wbase;
                #pragma unroll
                for (int jj = 0; jj < 8; ++jj) tmp[jj] = wp[(size_t)jj*kk];
            } else {
                const float* wp = (const float*)w + wbase;
                #pragma unroll
                for (int jj = 0; jj < 8; ++jj) tmp[jj] = f2bf(wp[(size_t)jj*kk]);
            }
            bf16x8 bfr;
            __builtin_memcpy(&bfr, tmp, 16);
            acc[cg] = __builtin_amdgcn_mfma_f32_16x16x32_bf16(a, bfr, acc[cg], 0, 0, 0);
        }
    }

    const int rbase = m0 + wvv*16 + quad*4;
    if (bfm){
        ushort* outh = (ushort*)out;
        #pragma unroll
        for (int cg = 0; cg < 4; ++cg)
            #pragma unroll
            for (int rr = 0; rr < 4; ++rr){
                int grow = rbase + rr;
                if (grow < cnt)
                    outh[((size_t)b*SS + off_j + grow)*768 + n0 + cg*16 + l15] = f2bf(acc[cg][rr]);
            }
    } else {
        float* outf = (float*)out;
        #pragma unroll
        for (int cg = 0; cg < 4; ++cg)
            #pragma unroll
            for (int rr = 0; rr < 4; ++rr){
                int grow = rbase + rr;
                if (grow < cnt)
                    outf[((size_t)b*SS + off_j + grow)*768 + n0 + cg*16 + l15] = acc[cg][rr];
            }
    }
}

// ---------------------------------------------------------------------------
extern "C" void kernel_launch(void* const* d_in, const int* in_sizes, int n_in,
                              void* d_out, int out_size, void* d_ws, size_t ws_size,
                              hipStream_t stream) {
    const void* feat = d_in[0];
    const int*  mask = (const int*)d_in[1];

    const void* w[7]  = {0,0,0,0,0,0,0};
    const void* bs[7] = {0,0,0,0,0,0,0};
    int bi = 0;
    for (int i = 3; i < n_in; ++i){
        if (in_sizes[i] == 768){
            if (bi < 7) bs[bi++] = d_in[i];
        } else {
            int kk = in_sizes[i] / 589824;
            if (kk >= 2 && kk <= 8) w[kk-2] = d_in[i];
        }
    }

    // ws layout
    char* ws = (char*)d_ws;
    int*    flag    = (int*)ws;                       // @0
    int*    offs    = (int*)(ws + 64);                // 1152 B
    int*    pfx     = (int*)(ws + 2048);              // 924 B
    float*  biasF   = (float*)(ws + 4096);            // 21504 B
    int*    amap    = (int*)(ws + 28672);             // 7*6400*4 = 179200
    int*    omap    = (int*)(ws + 28672 + 179200);    // 179200 -> end 387072
    ushort* featbf  = (ushort*)(ws + 393216);         // 9,830,400
    ushort* Bp      = (ushort*)(ws + 393216 + 9830400); // 41,287,680
    const size_t FULL_BYTES = 393216ull + 9830400ull + 41287680ull;  // 51,511,296
    const bool use_full = ws_size >= FULL_BYTES;

    hipLaunchKernelGGL(detect_kernel, dim3(1), dim3(256), 0, stream,
                       (const unsigned int*)feat, flag);
    hipLaunchKernelGGL(offs_kernel, dim3(BB), dim3(64), 0, stream, mask, offs);

    if (use_full){
        hipLaunchKernelGGL(repack2_kernel, dim3(192, 7), dim3(256), 0, stream,
                           w[0], w[1], w[2], w[3], w[4], w[5], w[6],
                           bs[0], bs[1], bs[2], bs[3], bs[4], bs[5], bs[6],
                           Bp, biasF, flag);
        hipLaunchKernelGGL(cvtA_kernel, dim3(2400), dim3(256), 0, stream, feat, featbf, flag);
        hipLaunchKernelGGL(maps_kernel, dim3(7), dim3(256), 0, stream, offs, pfx, amap, omap);
    }

    hipLaunchKernelGGL(fill_kernel, dim3((BB*SS*192 + 255)/256), dim3(256), 0, stream,
                       feat, offs, d_out, flag);

    if (use_full){
        // 1D grid, 8 XCD classes x 300 slots (inactive slots exit immediately)
        hipLaunchKernelGGL(conv_gemm4, dim3(2400), dim3(256), 0, stream,
                           featbf, Bp, biasF, pfx, amap, omap, d_out, flag);
    } else {
        hipLaunchKernelGGL(conv_gemm_direct, dim3(48, 7, BB), dim3(256), 0, stream,
                           feat, offs, d_out, flag,
                           w[0], w[1], w[2], w[3], w[4], w[5], w[6],
                           bs[0], bs[1], bs[2], bs[3], bs[4], bs[5], bs[6]);
    }
}

// Round 4
// 562.749 us; speedup vs baseline: 1.2470x; 1.2470x over previous
//
#include <hip/hip_runtime.h>
#include <hip/hip_bf16.h>

#define BB 32
#define LL 200
#define DD 768
#define SS 1556
#define MAXM 6400   // per-kk flattened row capacity (32 * (199-kk) < 6400)

typedef __attribute__((ext_vector_type(8))) short bf16x8;   // 8 bf16 = 4 VGPRs (MFMA A/B frag)
typedef __attribute__((ext_vector_type(4))) float floatx4;  // MFMA C/D frag

__device__ __forceinline__ float bf2f(ushort u){
    union { unsigned int i; float f; } v; v.i = ((unsigned int)u) << 16; return v.f;
}
__device__ __forceinline__ ushort f2bf(float f){
    union { float f; unsigned int i; } v; v.f = f;
    unsigned int x = v.i;
    return (ushort)((x + 0x7FFFu + ((x >> 16) & 1u)) >> 16);  // RNE, inputs finite
}

// XCD schedule tables in .rodata (scalar-loaded; runtime-indexed local arrays
// would go to scratch per rule #20).
__device__ const int GCNT_C[8] = {5,5,5,5,5,5,6,6};
__device__ const int GLIST_C[8][6] = {
    {36,37,38, 0, 4, 0},   // kk8 x3 + kk2 x2
    {39,40,41, 1, 5, 0},   // kk8 x3 + kk2 x2
    {30,31,32, 6, 2, 0},   // kk7 x3 + kk3 + kk2
    {33,34,35, 7, 3, 0},   // kk7 x3 + kk3 + kk2
    {24,25,26,12,13, 0},   // kk6 x3 + kk4 x2
    {27,28,29,14,15, 0},   // kk6 x3 + kk4 x2
    {18,19,20,16, 8,10},   // kk5 x3 + kk4 + kk3 x2
    {21,22,23,17, 9,11},   // kk5 x3 + kk4 + kk3 x2
};

// ---------------------------------------------------------------------------
// Kernel 0: dtype detector (flag=1 -> bf16 data, flag=0 -> float32).
// ---------------------------------------------------------------------------
__global__ void detect_kernel(const unsigned int* __restrict__ feat_raw, int* __restrict__ flag){
    __shared__ int cnt_s;
    if (threadIdx.x == 0) cnt_s = 0;
    __syncthreads();
    int c = 0;
    for (int i = threadIdx.x; i < 4096; i += 256){
        unsigned int w = feat_raw[i];
        unsigned int e = (w >> 7) & 0xFFu;
        if (e >= 100u && e <= 150u) c++;
    }
    atomicAdd(&cnt_s, c);
    __syncthreads();
    if (threadIdx.x == 0) *flag = (cnt_s > 2457) ? 1 : 0;
}

// ---------------------------------------------------------------------------
// Kernel 1: per-batch span offsets. offs[b][0..8]; counts[k] = max(n-k-2, 0).
// ---------------------------------------------------------------------------
__global__ void offs_kernel(const int* __restrict__ mask, int* __restrict__ offs){
    int b = blockIdx.x;
    int lane = threadIdx.x;
    int s = 0;
    for (int i = lane; i < LL; i += 64) s += mask[b*LL + i];
    #pragma unroll
    for (int d = 32; d > 0; d >>= 1) s += __shfl_down(s, d, 64);
    if (lane == 0){
        int n = s, cum = 0;
        offs[b*9 + 0] = 0;
        for (int j = 0; j < 8; ++j){
            int c = n - j - 2; if (c < 0) c = 0;
            cum += c;
            offs[b*9 + j + 1] = cum;
        }
    }
}

// ---------------------------------------------------------------------------
// Kernel 1b: flattened-M row maps per width bucket.
// ---------------------------------------------------------------------------
__global__ void maps_kernel(const int* __restrict__ offs, int* __restrict__ pfx,
                            int* __restrict__ amap, int* __restrict__ omap){
    const int kkidx = blockIdx.x;
    const int kk = kkidx + 2;
    __shared__ int P[33];
    __shared__ int base_s[32];
    const int tid = threadIdx.x;
    if (tid == 0){
        int acc = 0; P[0] = 0;
        for (int b = 0; b < 32; ++b){
            acc += offs[b*9 + kk] - offs[b*9 + kk - 1];
            P[b+1] = acc;
        }
    }
    if (tid < 32) base_s[tid] = offs[tid*9 + kk - 1];
    __syncthreads();
    if (tid == 0) pfx[kkidx*33 + 32] = P[32];
    const int Mtot = P[32];
    for (int r = tid; r < MAXM; r += 256){
        int b = 0;
        #pragma unroll
        for (int i = 1; i <= 32; ++i) b += (P[i] <= r) ? 1 : 0;
        int bb = b < 32 ? b : 31;
        int larow = (r < Mtot) ? (r - P[bb]) : 0;   // clamp OOB rows to a safe row
        amap[kkidx*MAXM + r] = bb*LL + larow + 1;
        omap[kkidx*MAXM + r] = bb*SS + base_s[bb] + larow;
    }
}

// ---------------------------------------------------------------------------
// Kernel 2: ALL widths' weight repack in ONE launch. grid=(192, 7).
// ---------------------------------------------------------------------------
__global__ void repack2_kernel(const void* __restrict__ w2, const void* __restrict__ w3,
                               const void* __restrict__ w4, const void* __restrict__ w5,
                               const void* __restrict__ w6, const void* __restrict__ w7,
                               const void* __restrict__ w8,
                               const void* __restrict__ b2, const void* __restrict__ b3,
                               const void* __restrict__ b4, const void* __restrict__ b5,
                               const void* __restrict__ b6, const void* __restrict__ b7,
                               const void* __restrict__ b8,
                               ushort* __restrict__ BpAll, float* __restrict__ biasF,
                               const int* __restrict__ flag){
    const int kkidx = blockIdx.y;
    const int kk = kkidx + 2;
    const void* w  = kkidx==0?w2:kkidx==1?w3:kkidx==2?w4:kkidx==3?w5:kkidx==4?w6:kkidx==5?w7:w8;
    const void* bv = kkidx==0?b2:kkidx==1?b3:kkidx==2?b4:kkidx==3?b5:kkidx==4?b6:kkidx==5?b7:b8;
    ushort* Bp = BpAll + (size_t)(kkidx*(kkidx+3)/2)*589824;   // PRE[kkidx]

    const int bfm = *flag;
    __shared__ ushort lds[24576];         // 4 rows x 768*8 max (49152 B)
    const int tid = threadIdx.x;
    const int ob  = blockIdx.x;           // 4 output channels each
    const int rowlen = DD * kk;
    const int nelem  = 4 * rowlen;

    if (bfm){
        const ushort* src = (const ushort*)w + (size_t)ob * nelem;
        const int nch = nelem >> 3;
        for (int c = tid; c < nch; c += 256)
            __builtin_memcpy(lds + c*8, src + c*8, 16);
        if (ob == 0)
            for (int i = tid; i < DD; i += 256) biasF[kkidx*DD + i] = bf2f(((const ushort*)bv)[i]);
    } else {
        const float* src = (const float*)w + (size_t)ob * nelem;
        const int nch = nelem >> 2;
        for (int c = tid; c < nch; c += 256){
            float t4[4];
            __builtin_memcpy(t4, src + c*4, 16);
            #pragma unroll
            for (int j2 = 0; j2 < 4; ++j2) lds[c*4 + j2] = f2bf(t4[j2]);
        }
        if (ob == 0)
            for (int i = tid; i < DD; i += 256) biasF[kkidx*DD + i] = ((const float*)bv)[i];
    }
    __syncthreads();

    const int total = 96 * kk * 4;
    for (int c = tid; c < total; c += 256){
        int jb = c >> 2, ol = c & 3;
        int j0 = jb * 8;
        int t  = j0 / 768;
        int i0 = j0 - t * 768;
        ushort tmp[8];
        #pragma unroll
        for (int jj = 0; jj < 8; ++jj)
            tmp[jj] = lds[ol*rowlen + (i0 + jj)*kk + t];
        int o = ob*4 + ol;
        __builtin_memcpy(Bp + (size_t)jb*6144 + (size_t)o*8, tmp, 16);
    }
}

// ---------------------------------------------------------------------------
// Kernel 2b: features -> bf16 A-source buffer.
// ---------------------------------------------------------------------------
__global__ void cvtA_kernel(const void* __restrict__ feat, ushort* __restrict__ featbf,
                            const int* __restrict__ flag){
    const int bfm = *flag;
    int idx = blockIdx.x*256 + threadIdx.x;
    const int TOT = BB*LL*DD/8;
    if (idx >= TOT) return;
    if (bfm){
        __builtin_memcpy(featbf + (size_t)idx*8, (const ushort*)feat + (size_t)idx*8, 16);
    } else {
        float t8[8];
        __builtin_memcpy(t8,     (const float*)feat + (size_t)idx*8,     16);
        __builtin_memcpy(t8 + 4, (const float*)feat + (size_t)idx*8 + 4, 16);
        ushort o8[8];
        #pragma unroll
        for (int j = 0; j < 8; ++j) o8[j] = f2bf(t8[j]);
        __builtin_memcpy(featbf + (size_t)idx*8, o8, 16);
    }
}

// ---------------------------------------------------------------------------
// Kernel 3: unigram copy + zero invalid + valid flags (native dtype).
// ---------------------------------------------------------------------------
__global__ void fill_kernel(const void* __restrict__ feat, const int* __restrict__ offs,
                            void* __restrict__ out, const int* __restrict__ flag){
    const int bfm = *flag;
    int idx = blockIdx.x*256 + threadIdx.x;
    const int TOT = BB*SS*192;
    if (idx >= TOT) return;
    int b = idx / (SS*192);
    int r = idx - b*(SS*192);
    int s = r / 192;
    int c = r - s*192;
    int c0  = offs[b*9 + 1];
    int tot = offs[b*9 + 8];
    if (bfm){
        if (c < 96){
            ushort* dst = (ushort*)out + ((size_t)b*SS + s)*768 + c*8;
            if (s < c0){
                const ushort* srcp = (const ushort*)feat + ((size_t)b*LL + s + 1)*768 + c*8;
                __builtin_memcpy(dst, srcp, 16);
            } else if (s >= tot){
                const ushort z[8] = {0,0,0,0,0,0,0,0};
                __builtin_memcpy(dst, z, 16);
            }
        }
        if (c == 0)
            ((ushort*)out)[(size_t)BB*SS*768 + (size_t)b*SS + s] = (s < tot) ? (ushort)0x3F80 : (ushort)0;
    } else {
        float* dst = (float*)out + ((size_t)b*SS + s)*768 + c*4;
        if (s < c0){
            const float* srcp = (const float*)feat + ((size_t)b*LL + s + 1)*768 + c*4;
            __builtin_memcpy(dst, srcp, 16);
        } else if (s >= tot){
            const float z[4] = {0.f,0.f,0.f,0.f};
            __builtin_memcpy(dst, z, 16);
        }
        if (c == 0)
            ((float*)out)[(size_t)BB*SS*768 + (size_t)b*SS + s] = (s < tot) ? 1.0f : 0.0f;
    }
}

// ---------------------------------------------------------------------------
// Kernel 4 (v4): both operands LDS-staged, traffic-minimized GEMM.
//  - A staged via global_load_lds in FRAGMENT order (per-lane scattered src,
//    linear dest) -> eliminates the wvn-pair duplicate A reads (-33% traffic)
//    and makes every ds_read lane-linear (conflict-free, no swizzle).
//  - B staged via global_load_lds as before.
//  - 2+2 LDS buffers (64 KB), period-2 counted-vmcnt pipeline: issue
//    A(ch+1),B(ch+1); vmcnt(8); barrier; compute(ch); barrier.
//  - nt-PAIR-major XCD order: co-resident blocks per XCD share ~2 B slices
//    (~3 MB, L2-fits) instead of 5-6 (5.3 MB thrash) -> B/A become L2 hits.
//  - schedule tables in rodata (no scratch).
// ---------------------------------------------------------------------------
__global__ __launch_bounds__(256) void conv_gemm5(const ushort* __restrict__ featbf,
        const ushort* __restrict__ BpAll, const float* __restrict__ biasF,
        const int* __restrict__ pfx, const int* __restrict__ amap,
        const int* __restrict__ omap, void* __restrict__ out,
        const int* __restrict__ flag){
    const int n   = blockIdx.x;
    const int xcd = n & 7;
    const int is  = n >> 3;
    const int cx  = GCNT_C[xcd];
    if (is >= cx * 50) return;
    // pair-major: consecutive slots alternate within a PAIR of groups so the
    // co-resident window covers only ~2 B-slices (L2-resident).
    int p = is / 100;
    int r = is - p*100;
    int gi, mt;
    if (2*p + 1 < cx){ gi = 2*p + (r & 1); mt = r >> 1; }
    else             { gi = 2*p;           mt = r;      }
    const int g  = GLIST_C[xcd][gi];
    const int kkidx = g / 6;
    const int nt = g - kkidx*6;
    const int kk = kkidx + 2;
    const int Mtot = pfx[kkidx*33 + 32];
    const int m0 = mt * 128;
    if (m0 >= Mtot) return;
    const int n0 = nt * 128;
    const int bfm = *flag;

    __shared__ ushort BsA[2][8192];        // 2 x 16 KB, fragment-ordered
    __shared__ ushort BsB[2][8192];        // 2 x 16 KB: 8 planes x 128 cols x 8

    const int tid  = threadIdx.x;
    const int wv   = tid >> 6;
    const int wvm  = wv >> 1;              // wave row (0..1)
    const int wvn  = wv & 1;               // wave col (0..1)
    const int lane = tid & 63;
    const int quad = lane >> 4;
    const int l15  = lane & 15;
    const int wvbase = tid & 192;          // wv*64 (wave-uniform)

    // A staging source pointers. Segment g2 = j*4+wv encodes (wvm,sm,ks):
    // g2 = wvm*8 + sm*2 + ks. Lane (quad,l15) supplies
    // featbf[amap(m0 + wvm*64 + sm*16 + l15)][ks*32 + quad*8 ..+8].
    const ushort* srcA[4];
    #pragma unroll
    for (int j = 0; j < 4; ++j){
        int g2 = j*4 + wv;
        int wvm_s = g2 >> 3, sm_s = (g2 >> 1) & 3, ks_s = g2 & 1;
        int rr = kkidx*MAXM + m0 + wvm_s*64 + sm_s*16 + l15;
        srcA[j] = featbf + (size_t)amap[rr]*768 + ks_s*32 + quad*8;
    }

    floatx4 acc[4][4];
    #pragma unroll
    for (int sn = 0; sn < 4; ++sn){
        float bv = biasF[kkidx*768 + n0 + wvn*64 + sn*16 + l15];
        #pragma unroll
        for (int sm = 0; sm < 4; ++sm){
            acc[sm][sn][0] = bv; acc[sm][sn][1] = bv;
            acc[sm][sn][2] = bv; acc[sm][sn][3] = bv;
        }
    }

    // B source: per-lane base; plane p = (tid>>7), col = n0 + (tid&127)
    const ushort* BkkBase = BpAll + (size_t)(kkidx*(kkidx+3)/2)*589824;
    const ushort* bsrc0 = BkkBase + (size_t)(tid >> 7)*6144 + (size_t)(n0 + (tid & 127))*8;
    char* ldsA = (char*)&BsA[0][0];
    char* ldsB = (char*)&BsB[0][0];
    const int nchunks = kk * 12;           // K / 64, always even

    #define STAGE_A(ABUF, ch) do { \
        _Pragma("unroll") \
        for (int j_ = 0; j_ < 4; ++j_){ \
            __builtin_amdgcn_global_load_lds( \
                (const __attribute__((address_space(1))) void*)(srcA[j_] + (ch)*64), \
                (__attribute__((address_space(3))) void*)(ldsA + (ABUF)*16384 + (j_*256 + wvbase)*16), \
                16, 0, 0); \
        } } while(0)

    #define STAGE_B(BBUF, ch) do { \
        const ushort* gb_ = bsrc0 + (size_t)(ch)*8*6144; \
        _Pragma("unroll") \
        for (int ii_ = 0; ii_ < 4; ++ii_){ \
            __builtin_amdgcn_global_load_lds( \
                (const __attribute__((address_space(1))) void*)(gb_ + (size_t)ii_*2*6144), \
                (__attribute__((address_space(3))) void*)(ldsB + (BBUF)*16384 + (ii_*256 + wvbase)*16), \
                16, 0, 0); \
        } } while(0)

    #define COMPUTE(ABUF, BBUF) do { \
        __builtin_amdgcn_s_setprio(1); \
        _Pragma("unroll") \
        for (int ks_ = 0; ks_ < 2; ++ks_){ \
            const int pl_ = ks_*4 + quad; \
            bf16x8 afr[4], bfr[4]; \
            _Pragma("unroll") \
            for (int sm_ = 0; sm_ < 4; ++sm_) \
                __builtin_memcpy(&afr[sm_], \
                    ldsA + (ABUF)*16384 + (wvm*8 + sm_*2 + ks_)*1024 + lane*16, 16); \
            _Pragma("unroll") \
            for (int sn_ = 0; sn_ < 4; ++sn_) \
                __builtin_memcpy(&bfr[sn_], &BsB[BBUF][pl_*1024 + (wvn*64 + sn_*16 + l15)*8], 16); \
            _Pragma("unroll") \
            for (int sm_ = 0; sm_ < 4; ++sm_) \
                _Pragma("unroll") \
                for (int sn_ = 0; sn_ < 4; ++sn_) \
                    acc[sm_][sn_] = __builtin_amdgcn_mfma_f32_16x16x32_bf16( \
                        afr[sm_], bfr[sn_], acc[sm_][sn_], 0, 0, 0); \
        } \
        __builtin_amdgcn_s_setprio(0); \
        } while(0)

    // Substep: issue next chunk's A+B (8 VMEM), wait for current chunk
    // (vmcnt(8) keeps next chunk in flight across both barriers), compute.
    #define SUBSTEP(CH, CUR, NXT, DO, NW) do { \
        if (DO){ STAGE_A(NXT, (CH)+1); STAGE_B(NXT, (CH)+1); } \
        __builtin_amdgcn_sched_barrier(0); \
        asm volatile("s_waitcnt vmcnt(" NW ")" ::: "memory"); \
        __builtin_amdgcn_sched_barrier(0); \
        __builtin_amdgcn_s_barrier(); \
        __builtin_amdgcn_sched_barrier(0); \
        COMPUTE(CUR, CUR); \
        __builtin_amdgcn_s_barrier(); \
        __builtin_amdgcn_sched_barrier(0); \
    } while(0)

    // prologue: chunk 0 in flight (A0:4, B0:4)
    STAGE_A(0, 0);
    STAGE_B(0, 0);

    for (int ch = 0; ch < nchunks - 2; ch += 2){
        SUBSTEP(ch,   0, 1, true, "8");
        SUBSTEP(ch+1, 1, 0, true, "8");
    }
    SUBSTEP(nchunks-2, 0, 1, true,  "8");
    SUBSTEP(nchunks-1, 1, 0, false, "0");

    #undef SUBSTEP
    #undef STAGE_A
    #undef STAGE_B
    #undef COMPUTE

    // ---- epilogue: scatter rows to packed span slots ----
    #pragma unroll
    for (int sm = 0; sm < 4; ++sm){
        #pragma unroll
        for (int rr = 0; rr < 4; ++rr){
            int r2 = m0 + wvm*64 + sm*16 + quad*4 + rr;
            if (r2 < Mtot){
                int slot = omap[kkidx*MAXM + r2];
                if (bfm){
                    ushort* oh = (ushort*)out;
                    #pragma unroll
                    for (int sn = 0; sn < 4; ++sn)
                        oh[(size_t)slot*768 + n0 + wvn*64 + sn*16 + l15] = f2bf(acc[sm][sn][rr]);
                } else {
                    float* of = (float*)out;
                    #pragma unroll
                    for (int sn = 0; sn < 4; ++sn)
                        of[(size_t)slot*768 + n0 + wvn*64 + sn*16 + l15] = acc[sm][sn][rr];
                }
            }
        }
    }
}

// ---------------------------------------------------------------------------
// Fallback (workspace too small): direct-from-raw-weights GEMM. Slow, correct.
// ---------------------------------------------------------------------------
__global__ __launch_bounds__(256) void conv_gemm_direct(const void* __restrict__ feat,
        const int* __restrict__ offs, void* __restrict__ out, const int* __restrict__ flag,
        const void* w2, const void* w3, const void* w4, const void* w5,
        const void* w6, const void* w7, const void* w8,
        const void* b2, const void* b3, const void* b4, const void* b5,
        const void* b6, const void* b7, const void* b8){
    const int bfm = *flag;
    const int kkidx = blockIdx.y;
    const int kk = kkidx + 2;
    const int b = blockIdx.z;
    const void* w  = kkidx==0?w2:kkidx==1?w3:kkidx==2?w4:kkidx==3?w5:kkidx==4?w6:kkidx==5?w7:w8;
    const void* bv = kkidx==0?b2:kkidx==1?b3:kkidx==2?b4:kkidx==3?b5:kkidx==4?b6:kkidx==5?b7:b8;

    const int off_j = offs[b*9 + kk - 1];
    const int cnt   = offs[b*9 + kk] - off_j;
    const int mt = blockIdx.x / 12;
    const int nt = blockIdx.x - mt*12;
    const int m0 = mt * 64;
    if (m0 >= cnt) return;
    const int n0 = nt * 64;

    const int tid  = threadIdx.x;
    const int wvv  = tid >> 6;
    const int lane = tid & 63;
    const int quad = lane >> 4;
    const int l15  = lane & 15;

    int row  = m0 + wvv*16 + l15;
    int arow = row < cnt ? row : cnt - 1;
    const size_t abase = ((size_t)b*LL + arow + 1)*768 + quad*8;

    floatx4 acc[4];
    #pragma unroll
    for (int cg = 0; cg < 4; ++cg){
        float bb = bfm ? bf2f(((const ushort*)bv)[n0 + cg*16 + l15])
                       : ((const float*)bv)[n0 + cg*16 + l15];
        acc[cg][0] = bb; acc[cg][1] = bb; acc[cg][2] = bb; acc[cg][3] = bb;
    }

    const int steps = kk * 24;
    for (int s = 0; s < steps; ++s){
        bf16x8 a;
        if (bfm){
            __builtin_memcpy(&a, (const ushort*)feat + abase + s*32, 16);
        } else {
            float t8[8];
            __builtin_memcpy(t8,     (const float*)feat + abase + s*32,     16);
            __builtin_memcpy(t8 + 4, (const float*)feat + abase + s*32 + 4, 16);
            ushort o8[8];
            #pragma unroll
            for (int j = 0; j < 8; ++j) o8[j] = f2bf(t8[j]);
            __builtin_memcpy(&a, o8, 16);
        }
        int j0 = s*32 + quad*8;
        int t  = j0 / 768;
        int i0 = j0 - t*768;
        #pragma unroll
        for (int cg = 0; cg < 4; ++cg){
            int o = n0 + cg*16 + l15;
            size_t wbase = (size_t)o*(DD*kk) + (size_t)i0*kk + t;
            ushort tmp[8];
            if (bfm){
                const ushort* wp = (const ushort*)w + wbase;
                #pragma unroll
                for (int jj = 0; jj < 8; ++jj) tmp[jj] = wp[(size_t)jj*kk];
            } else {
                const float* wp = (const float*)w + wbase;
                #pragma unroll
                for (int jj = 0; jj < 8; ++jj) tmp[jj] = f2bf(wp[(size_t)jj*kk]);
            }
            bf16x8 bfr;
            __builtin_memcpy(&bfr, tmp, 16);
            acc[cg] = __builtin_amdgcn_mfma_f32_16x16x32_bf16(a, bfr, acc[cg], 0, 0, 0);
        }
    }

    const int rbase = m0 + wvv*16 + quad*4;
    if (bfm){
        ushort* outh = (ushort*)out;
        #pragma unroll
        for (int cg = 0; cg < 4; ++cg)
            #pragma unroll
            for (int rr = 0; rr < 4; ++rr){
                int grow = rbase + rr;
                if (grow < cnt)
                    outh[((size_t)b*SS + off_j + grow)*768 + n0 + cg*16 + l15] = f2bf(acc[cg][rr]);
            }
    } else {
        float* outf = (float*)out;
        #pragma unroll
        for (int cg = 0; cg < 4; ++cg)
            #pragma unroll
            for (int rr = 0; rr < 4; ++rr){
                int grow = rbase + rr;
                if (grow < cnt)
                    outf[((size_t)b*SS + off_j + grow)*768 + n0 + cg*16 + l15] = acc[cg][rr];
            }
    }
}

// ---------------------------------------------------------------------------
extern "C" void kernel_launch(void* const* d_in, const int* in_sizes, int n_in,
                              void* d_out, int out_size, void* d_ws, size_t ws_size,
                              hipStream_t stream) {
    const void* feat = d_in[0];
    const int*  mask = (const int*)d_in[1];

    const void* w[7]  = {0,0,0,0,0,0,0};
    const void* bs[7] = {0,0,0,0,0,0,0};
    int bi = 0;
    for (int i = 3; i < n_in; ++i){
        if (in_sizes[i] == 768){
            if (bi < 7) bs[bi++] = d_in[i];
        } else {
            int kk = in_sizes[i] / 589824;
            if (kk >= 2 && kk <= 8) w[kk-2] = d_in[i];
        }
    }

    // ws layout
    char* ws = (char*)d_ws;
    int*    flag    = (int*)ws;                       // @0
    int*    offs    = (int*)(ws + 64);                // 1152 B
    int*    pfx     = (int*)(ws + 2048);              // 924 B
    float*  biasF   = (float*)(ws + 4096);            // 21504 B
    int*    amap    = (int*)(ws + 28672);             // 7*6400*4 = 179200
    int*    omap    = (int*)(ws + 28672 + 179200);    // 179200 -> end 387072
    ushort* featbf  = (ushort*)(ws + 393216);         // 9,830,400
    ushort* Bp      = (ushort*)(ws + 393216 + 9830400); // 41,287,680
    const size_t FULL_BYTES = 393216ull + 9830400ull + 41287680ull;  // 51,511,296
    const bool use_full = ws_size >= FULL_BYTES;

    hipLaunchKernelGGL(detect_kernel, dim3(1), dim3(256), 0, stream,
                       (const unsigned int*)feat, flag);
    hipLaunchKernelGGL(offs_kernel, dim3(BB), dim3(64), 0, stream, mask, offs);

    if (use_full){
        hipLaunchKernelGGL(repack2_kernel, dim3(192, 7), dim3(256), 0, stream,
                           w[0], w[1], w[2], w[3], w[4], w[5], w[6],
                           bs[0], bs[1], bs[2], bs[3], bs[4], bs[5], bs[6],
                           Bp, biasF, flag);
        hipLaunchKernelGGL(cvtA_kernel, dim3(2400), dim3(256), 0, stream, feat, featbf, flag);
        hipLaunchKernelGGL(maps_kernel, dim3(7), dim3(256), 0, stream, offs, pfx, amap, omap);
    }

    hipLaunchKernelGGL(fill_kernel, dim3((BB*SS*192 + 255)/256), dim3(256), 0, stream,
                       feat, offs, d_out, flag);

    if (use_full){
        // 1D grid, 8 XCD classes x 300 slots (inactive slots exit immediately)
        hipLaunchKernelGGL(conv_gemm5, dim3(2400), dim3(256), 0, stream,
                           featbf, Bp, biasF, pfx, amap, omap, d_out, flag);
    } else {
        hipLaunchKernelGGL(conv_gemm_direct, dim3(48, 7, BB), dim3(256), 0, stream,
                           feat, offs, d_out, flag,
                           w[0], w[1], w[2], w[3], w[4], w[5], w[6],
                           bs[0], bs[1], bs[2], bs[3], bs[4], bs[5], bs[6]);
    }
}